// Round 2
// baseline (746.464 us; speedup 1.0000x reference)
//
#include <hip/hip_runtime.h>

#define NP 2048
#define BB 8
#define DIM 256
#define NROW 16384
#define N_ITER 8
#define INV_T 14.2857142857142857f
#define LOG2047 7.624130539966131f
#define AB_CONST 4.8828125e-4f   // 1/2048

typedef unsigned short u16;
typedef __attribute__((ext_vector_type(4))) float f32x4;
typedef __attribute__((ext_vector_type(8))) short bf16x8;

static __device__ __forceinline__ u16 f2bf(float x) {
    unsigned u = __float_as_uint(x);
    unsigned r = (u + 0x7FFFu + ((u >> 16) & 1u)) >> 16;
    return (u16)r;
}
static __device__ __forceinline__ float bf2f(u16 h) {
    return __uint_as_float(((unsigned)h) << 16);
}

// ---------------- Kernel 1: norms, l_pos, bf16 casts, zero s[0] ----------------
__global__ __launch_bounds__(256) void k_prep(const float* __restrict__ q,
        const float* __restrict__ kk, u16* __restrict__ qb, u16* __restrict__ kb,
        float* __restrict__ rnq, float* __restrict__ rnk,
        float* __restrict__ lpos, float* __restrict__ s0) {
    int tid = threadIdx.x;
    int w = tid >> 6, l = tid & 63;
    int row = blockIdx.x * 4 + w;            // grid 4096 -> 16384 rows
    float4 qv = *(const float4*)(q + (size_t)row * DIM + l * 4);
    float4 kv = *(const float4*)(kk + (size_t)row * DIM + l * 4);
    float sq = qv.x*qv.x + qv.y*qv.y + qv.z*qv.z + qv.w*qv.w;
    float sk = kv.x*kv.x + kv.y*kv.y + kv.z*kv.z + kv.w*kv.w;
    float dq = qv.x*kv.x + qv.y*kv.y + qv.z*kv.z + qv.w*kv.w;
    #pragma unroll
    for (int off = 32; off; off >>= 1) {
        sq += __shfl_xor(sq, off);
        sk += __shfl_xor(sk, off);
        dq += __shfl_xor(dq, off);
    }
    ushort4 qh, kh;
    qh.x = f2bf(qv.x); qh.y = f2bf(qv.y); qh.z = f2bf(qv.z); qh.w = f2bf(qv.w);
    kh.x = f2bf(kv.x); kh.y = f2bf(kv.y); kh.z = f2bf(kv.z); kh.w = f2bf(kv.w);
    *(ushort4*)(qb + (size_t)row * DIM + l * 4) = qh;
    *(ushort4*)(kb + (size_t)row * DIM + l * 4) = kh;
    if (l == 0) {
        rnq[row] = 1.0f / fmaxf(sqrtf(sq), 1e-12f);
        rnk[row] = 1.0f / fmaxf(sqrtf(sk), 1e-12f);
        lpos[row] = dq;
    }
    if (blockIdx.x < 64) s0[blockIdx.x * 256 + tid] = 0.0f;
}

// ---------------- Kernel 2: per-batch Gram GEMM -> G(bf16), K=exp(-C)(bf16) ----
__global__ __launch_bounds__(256) void k_gemm(const u16* __restrict__ qb,
    const u16* __restrict__ kb, const float* __restrict__ rnq,
    const float* __restrict__ rnk, u16* __restrict__ G, u16* __restrict__ Kx) {
    __shared__ u16 As[128 * 72];
    __shared__ u16 Bs[128 * 72];
    int b = blockIdx.z;
    int i0 = blockIdx.y * 128, j0 = blockIdx.x * 128;
    int tid = threadIdx.x, l = tid & 63, w = tid >> 6;
    int wr = w >> 1, wc = w & 1;
    int rl = l & 15, kg = l >> 4;
    f32x4 acc[4][4] = {};
    for (int kt = 0; kt < 4; ++kt) {
        __syncthreads();
        #pragma unroll
        for (int it = 0; it < 4; ++it) {
            int qd = tid + it * 256;
            int rr = qd >> 3;
            int c8 = (qd & 7) * 8;
            uint4 av = *(const uint4*)(qb + ((size_t)(b * NP + i0 + rr)) * DIM + kt * 64 + c8);
            *(uint4*)(As + rr * 72 + c8) = av;
            uint4 bv = *(const uint4*)(kb + ((size_t)(b * NP + j0 + rr)) * DIM + kt * 64 + c8);
            *(uint4*)(Bs + rr * 72 + c8) = bv;
        }
        __syncthreads();
        #pragma unroll
        for (int kkx = 0; kkx < 2; ++kkx) {
            bf16x8 af[4], bfr[4];
            int ko = kkx * 32 + kg * 8;
            #pragma unroll
            for (int mi = 0; mi < 4; ++mi)
                af[mi] = *(const bf16x8*)(As + (wr * 64 + mi * 16 + rl) * 72 + ko);
            #pragma unroll
            for (int ni = 0; ni < 4; ++ni)
                bfr[ni] = *(const bf16x8*)(Bs + (wc * 64 + ni * 16 + rl) * 72 + ko);
            #pragma unroll
            for (int mi = 0; mi < 4; ++mi)
                #pragma unroll
                for (int ni = 0; ni < 4; ++ni)
                    acc[mi][ni] = __builtin_amdgcn_mfma_f32_16x16x32_bf16(af[mi], bfr[ni], acc[mi][ni], 0, 0, 0);
        }
    }
    #pragma unroll
    for (int mi = 0; mi < 4; ++mi) {
        #pragma unroll
        for (int r = 0; r < 4; ++r) {
            int m = i0 + wr * 64 + mi * 16 + kg * 4 + r;
            float rq = rnq[b * NP + m];
            #pragma unroll
            for (int ni = 0; ni < 4; ++ni) {
                int n = j0 + wc * 64 + ni * 16 + rl;
                float g = acc[mi][ni][r];
                float rk = rnk[b * NP + n];
                size_t off = ((size_t)(b * NP + m) << 11) + n;
                G[off] = f2bf(g);
                Kx[off] = f2bf(__expf(-g * rq * rk));
            }
        }
    }
}

// ---------------- Kernel 3: fused Sinkhorn iteration, single K pass ------------
// v = b/(s_prev+eps) (or uniform), u = a/(Kv+eps), s_cur += u^T K, K loaded ONCE
__global__ __launch_bounds__(512, 4) void k_sink(const u16* __restrict__ Kx,
    const float* __restrict__ s_prev, float* __restrict__ s_cur,
    float* __restrict__ s_zero, float* __restrict__ u, int first) {
    __shared__ float s_lds[NP];
    int tid = threadIdx.x, l = tid & 63, w = tid >> 6;   // 8 waves
    int b = blockIdx.x >> 6;            // 64 blocks per batch
    int m0 = (blockIdx.x & 63) * 32;    // 32 rows per block
    if (tid < 32) s_zero[blockIdx.x * 32 + tid] = 0.0f;
    for (int i = tid; i < NP; i += 512) s_lds[i] = 0.0f;
    float vreg[32];
    if (first) {
        #pragma unroll
        for (int i = 0; i < 32; ++i) vreg[i] = AB_CONST;
    } else {
        #pragma unroll
        for (int it = 0; it < 4; ++it) {
            float4 s0 = *(const float4*)(s_prev + b * NP + it * 512 + l * 8);
            float4 s1 = *(const float4*)(s_prev + b * NP + it * 512 + l * 8 + 4);
            vreg[it*8+0] = AB_CONST / (s0.x + 1e-8f);
            vreg[it*8+1] = AB_CONST / (s0.y + 1e-8f);
            vreg[it*8+2] = AB_CONST / (s0.z + 1e-8f);
            vreg[it*8+3] = AB_CONST / (s0.w + 1e-8f);
            vreg[it*8+4] = AB_CONST / (s1.x + 1e-8f);
            vreg[it*8+5] = AB_CONST / (s1.y + 1e-8f);
            vreg[it*8+6] = AB_CONST / (s1.z + 1e-8f);
            vreg[it*8+7] = AB_CONST / (s1.w + 1e-8f);
        }
    }
    __syncthreads();
    float sreg[32];
    #pragma unroll
    for (int i = 0; i < 32; ++i) sreg[i] = 0.0f;
    #pragma unroll
    for (int rr = 0; rr < 4; ++rr) {
        int row = m0 + w * 4 + rr;
        const u16* kp = Kx + ((size_t)(b * NP + row) << 11);
        uint4 kv0 = *(const uint4*)(kp + l * 8);
        uint4 kv1 = *(const uint4*)(kp + 512 + l * 8);
        uint4 kv2 = *(const uint4*)(kp + 1024 + l * 8);
        uint4 kv3 = *(const uint4*)(kp + 1536 + l * 8);
        float kf[32];
        const u16* h0 = (const u16*)&kv0;
        const u16* h1 = (const u16*)&kv1;
        const u16* h2 = (const u16*)&kv2;
        const u16* h3 = (const u16*)&kv3;
        #pragma unroll
        for (int j = 0; j < 8; ++j) {
            kf[j]      = bf2f(h0[j]);
            kf[8 + j]  = bf2f(h1[j]);
            kf[16 + j] = bf2f(h2[j]);
            kf[24 + j] = bf2f(h3[j]);
        }
        float p = 0.0f;
        #pragma unroll
        for (int j = 0; j < 32; ++j) p += kf[j] * vreg[j];
        #pragma unroll
        for (int off = 32; off; off >>= 1) p += __shfl_xor(p, off);
        float um = AB_CONST / (p + 1e-8f);
        if (l == 0) u[b * NP + row] = um;
        #pragma unroll
        for (int j = 0; j < 32; ++j) sreg[j] += kf[j] * um;
    }
    #pragma unroll
    for (int j = 0; j < 32; ++j)
        atomicAdd(&s_lds[(j >> 3) * 512 + l * 8 + (j & 7)], sreg[j]);
    __syncthreads();
    for (int i = tid; i < NP; i += 512)
        atomicAdd(&s_cur[b * NP + i], s_lds[i]);
}

// ---------------- Kernel 4: finalize log u, log v -----------------------------
__global__ __launch_bounds__(256) void k_logs(const float* __restrict__ s_fin,
        const float* __restrict__ u, float* __restrict__ logu, float* __restrict__ logv) {
    int gid = blockIdx.x * 256 + threadIdx.x;   // grid 64
    float vv = AB_CONST / (s_fin[gid] + 1e-8f);
    logv[gid] = logf(vv);
    logu[gid] = logf(u[gid]);
}

// ---------------- Kernel 5: logits + partial online LSE (4 j-chunks) ----------
__global__ __launch_bounds__(256, 4) void k_loss(const u16* __restrict__ G,
    const float* __restrict__ rnq, const float* __restrict__ rnk,
    const float* __restrict__ logu, const float* __restrict__ logv,
    float* __restrict__ pmo, float* __restrict__ pso) {
    __shared__ float Grow[64 * 65];
    __shared__ float Tcol[64 * 65];
    __shared__ float lu_s[64], rq_s[64];
    __shared__ float pm[4][64], ps[4][64];
    int tid = threadIdx.x;
    int r = tid & 63, p = tid >> 6;
    int chunk = blockIdx.x;           // 0..3
    int i0 = blockIdx.y * 64;         // 0..31 tiles
    int b = blockIdx.z;               // 0..7
    int gi = b * NP + i0 + r;
    int iloc = i0 + r;
    float rki = rnk[gi];
    float lvc = logv[gi] + LOG2047;
    float m = -1e30f;
    float ssum = 0.0f;
    for (int jtl = 0; jtl < 8; ++jtl) {
        int jb = (chunk * 8 + jtl) * 64;
        __syncthreads();
        #pragma unroll
        for (int s2 = 0; s2 < 2; ++s2) {
            int qd = tid + s2 * 256;
            int rr = qd >> 3;
            int c8 = (qd & 7) * 8;
            uint4 gv = *(const uint4*)(G + ((size_t)(b * NP + i0 + rr) << 11) + jb + c8);
            const u16* hs = (const u16*)&gv;
            #pragma unroll
            for (int d = 0; d < 8; ++d) Grow[rr * 65 + c8 + d] = bf2f(hs[d]);
            uint4 cv = *(const uint4*)(G + ((size_t)(b * NP + jb + rr) << 11) + i0 + c8);
            const u16* hc = (const u16*)&cv;
            #pragma unroll
            for (int d = 0; d < 8; ++d) Tcol[(c8 + d) * 65 + rr] = bf2f(hc[d]);
        }
        if (tid < 64) {
            lu_s[tid] = logu[b * NP + jb + tid];
            rq_s[tid] = rnq[b * NP + jb + tid];
        }
        __syncthreads();
        int j0 = p * 16;
        #pragma unroll
        for (int jj = 0; jj < 16; ++jj) {
            int jc = j0 + jj;
            float gij = Grow[r * 65 + jc];
            float gji = Tcol[r * 65 + jc];
            float logit = gij * INV_T - gji * rq_s[jc] * rki + lu_s[jc] + lvc;
            if (iloc == jb + jc) logit = -10.0f * INV_T;
            if (logit <= m) {
                ssum += __expf(logit - m);
            } else {
                ssum = ssum * __expf(m - logit) + 1.0f;
                m = logit;
            }
        }
    }
    pm[p][r] = m; ps[p][r] = ssum;
    __syncthreads();
    if (tid < 64) {
        float M = pm[0][tid];
        #pragma unroll
        for (int pp = 1; pp < 4; ++pp) M = fmaxf(M, pm[pp][tid]);
        float S = 0.0f;
        #pragma unroll
        for (int pp = 0; pp < 4; ++pp) S += ps[pp][tid] * __expf(pm[pp][tid] - M);
        int row = b * NP + i0 + tid;
        pmo[row * 4 + chunk] = M;
        pso[row * 4 + chunk] = S;
    }
}

// ---------------- Kernel 6: combine partials + positive -> loss ---------------
__global__ __launch_bounds__(256) void k_comb(const float* __restrict__ pmo,
        const float* __restrict__ pso, const float* __restrict__ lpos,
        float* __restrict__ out) {
    int gid = blockIdx.x * 256 + threadIdx.x;   // grid 64
    float opos = lpos[gid] * INV_T;
    float M = opos, S = 1.0f;
    float4 m4 = *(const float4*)(pmo + gid * 4);
    float4 s4 = *(const float4*)(pso + gid * 4);
    float mv[4] = {m4.x, m4.y, m4.z, m4.w};
    float sv[4] = {s4.x, s4.y, s4.z, s4.w};
    #pragma unroll
    for (int c = 0; c < 4; ++c) {
        float Mn = fmaxf(M, mv[c]);
        S = S * __expf(M - Mn) + sv[c] * __expf(mv[c] - Mn);
        M = Mn;
    }
    out[gid] = M + logf(S) - opos;
}

extern "C" void kernel_launch(void* const* d_in, const int* in_sizes, int n_in,
                              void* d_out, int out_size, void* d_ws, size_t ws_size,
                              hipStream_t stream) {
    const float* q = (const float*)d_in[0];
    const float* k = (const float*)d_in[1];
    char* w = (char*)d_ws;
    u16* G    = (u16*)(w);                          // 67108864 B
    u16* Kx   = (u16*)(w + 67108864);               // 67108864 B
    u16* qb   = (u16*)(w + 134217728);              // 8388608 B
    u16* kb   = (u16*)(w + 142606336);              // 8388608 B (dead after k_gemm)
    float* pmo  = (float*)(w + 142606336);          // overlaps kb: used only by k_loss/k_comb
    float* pso  = (float*)(w + 142606336 + 262144);
    float* rnq  = (float*)(w + 150994944);
    float* rnk  = (float*)(w + 151060480);
    float* lpos = (float*)(w + 151126016);
    float* u    = (float*)(w + 151191552);
    float* logu = (float*)(w + 151257088);
    float* logv = (float*)(w + 151322624);
    float* s    = (float*)(w + 151388160);          // 3 * 65536 B
    float* out  = (float*)d_out;

    k_prep<<<4096, 256, 0, stream>>>(q, k, qb, kb, rnq, rnk, lpos, s);
    k_gemm<<<dim3(16, 16, 8), 256, 0, stream>>>(qb, kb, rnq, rnk, G, Kx);
    for (int t = 0; t < N_ITER; ++t) {
        const float* sp = s + ((t + 2) % 3) * NROW;
        float* sc = s + (t % 3) * NROW;
        float* sz = s + ((t + 1) % 3) * NROW;
        k_sink<<<512, 512, 0, stream>>>(Kx, sp, sc, sz, u, t == 0 ? 1 : 0);
    }
    k_logs<<<64, 256, 0, stream>>>(s + ((N_ITER - 1) % 3) * NROW, u, logu, logv);
    k_loss<<<dim3(4, 32, 8), 256, 0, stream>>>(G, rnq, rnk, logu, logv, pmo, pso);
    k_comb<<<64, 256, 0, stream>>>(pmo, pso, lpos, out);
}

// Round 3
// 314.818 us; speedup vs baseline: 2.3711x; 2.3711x over previous
//
#include <hip/hip_runtime.h>

#define NP 2048
#define BB 8
#define DIM 256
#define NROW 16384
#define N_ITER 7
#define INV_T 14.2857142857142857f
#define LOG2047 7.624130539966131f
#define AB_CONST 4.8828125e-4f   // 1/2048

typedef unsigned short u16;
typedef __attribute__((ext_vector_type(4))) float f32x4;
typedef __attribute__((ext_vector_type(8))) short bf16x8;

static __device__ __forceinline__ u16 f2bf(float x) {
    unsigned u = __float_as_uint(x);
    unsigned r = (u + 0x7FFFu + ((u >> 16) & 1u)) >> 16;
    return (u16)r;
}
static __device__ __forceinline__ float bf2f(u16 h) {
    return __uint_as_float(((unsigned)h) << 16);
}

// ---------------- Kernel 1: norms, l_pos, bf16 casts ---------------------------
__global__ __launch_bounds__(256) void k_prep(const float* __restrict__ q,
        const float* __restrict__ kk, u16* __restrict__ qb, u16* __restrict__ kb,
        float* __restrict__ rnq, float* __restrict__ rnk,
        float* __restrict__ lpos) {
    int tid = threadIdx.x;
    int w = tid >> 6, l = tid & 63;
    int row = blockIdx.x * 4 + w;            // grid 4096 -> 16384 rows
    float4 qv = *(const float4*)(q + (size_t)row * DIM + l * 4);
    float4 kv = *(const float4*)(kk + (size_t)row * DIM + l * 4);
    float sq = qv.x*qv.x + qv.y*qv.y + qv.z*qv.z + qv.w*qv.w;
    float sk = kv.x*kv.x + kv.y*kv.y + kv.z*kv.z + kv.w*kv.w;
    float dq = qv.x*kv.x + qv.y*kv.y + qv.z*kv.z + qv.w*kv.w;
    #pragma unroll
    for (int off = 32; off; off >>= 1) {
        sq += __shfl_xor(sq, off);
        sk += __shfl_xor(sk, off);
        dq += __shfl_xor(dq, off);
    }
    ushort4 qh, kh;
    qh.x = f2bf(qv.x); qh.y = f2bf(qv.y); qh.z = f2bf(qv.z); qh.w = f2bf(qv.w);
    kh.x = f2bf(kv.x); kh.y = f2bf(kv.y); kh.z = f2bf(kv.z); kh.w = f2bf(kv.w);
    *(ushort4*)(qb + (size_t)row * DIM + l * 4) = qh;
    *(ushort4*)(kb + (size_t)row * DIM + l * 4) = kh;
    if (l == 0) {
        rnq[row] = 1.0f / fmaxf(sqrtf(sq), 1e-12f);
        rnk[row] = 1.0f / fmaxf(sqrtf(sk), 1e-12f);
        lpos[row] = dq;
    }
}

// ---------------- Kernel 2: per-batch Gram GEMM -> G(bf16), K=exp(-C)(bf16) ----
__global__ __launch_bounds__(256) void k_gemm(const u16* __restrict__ qb,
    const u16* __restrict__ kb, const float* __restrict__ rnq,
    const float* __restrict__ rnk, u16* __restrict__ G, u16* __restrict__ Kx) {
    __shared__ u16 As[128 * 72];
    __shared__ u16 Bs[128 * 72];
    int b = blockIdx.z;
    int i0 = blockIdx.y * 128, j0 = blockIdx.x * 128;
    int tid = threadIdx.x, l = tid & 63, w = tid >> 6;
    int wr = w >> 1, wc = w & 1;
    int rl = l & 15, kg = l >> 4;
    f32x4 acc[4][4] = {};
    for (int kt = 0; kt < 4; ++kt) {
        __syncthreads();
        #pragma unroll
        for (int it = 0; it < 4; ++it) {
            int qd = tid + it * 256;
            int rr = qd >> 3;
            int c8 = (qd & 7) * 8;
            uint4 av = *(const uint4*)(qb + ((size_t)(b * NP + i0 + rr)) * DIM + kt * 64 + c8);
            *(uint4*)(As + rr * 72 + c8) = av;
            uint4 bv = *(const uint4*)(kb + ((size_t)(b * NP + j0 + rr)) * DIM + kt * 64 + c8);
            *(uint4*)(Bs + rr * 72 + c8) = bv;
        }
        __syncthreads();
        #pragma unroll
        for (int kkx = 0; kkx < 2; ++kkx) {
            bf16x8 af[4], bfr[4];
            int ko = kkx * 32 + kg * 8;
            #pragma unroll
            for (int mi = 0; mi < 4; ++mi)
                af[mi] = *(const bf16x8*)(As + (wr * 64 + mi * 16 + rl) * 72 + ko);
            #pragma unroll
            for (int ni = 0; ni < 4; ++ni)
                bfr[ni] = *(const bf16x8*)(Bs + (wc * 64 + ni * 16 + rl) * 72 + ko);
            #pragma unroll
            for (int mi = 0; mi < 4; ++mi)
                #pragma unroll
                for (int ni = 0; ni < 4; ++ni)
                    acc[mi][ni] = __builtin_amdgcn_mfma_f32_16x16x32_bf16(af[mi], bfr[ni], acc[mi][ni], 0, 0, 0);
        }
    }
    #pragma unroll
    for (int mi = 0; mi < 4; ++mi) {
        #pragma unroll
        for (int r = 0; r < 4; ++r) {
            int m = i0 + wr * 64 + mi * 16 + kg * 4 + r;
            float rq = rnq[b * NP + m];
            #pragma unroll
            for (int ni = 0; ni < 4; ++ni) {
                int n = j0 + wc * 64 + ni * 16 + rl;
                float g = acc[mi][ni][r];
                float rk = rnk[b * NP + n];
                size_t off = ((size_t)(b * NP + m) << 11) + n;
                G[off] = f2bf(g);
                Kx[off] = f2bf(__expf(-g * rq * rk));
            }
        }
    }
}

// ---------------- Kernel 3: fused Sinkhorn iteration, no atomics ---------------
// v = b/(s_prev+eps) (or uniform), u = a/(Kv+eps), per-block partial of u^T K
__global__ __launch_bounds__(256, 4) void k_sink(const u16* __restrict__ Kx,
    const float* __restrict__ s_prev, float* __restrict__ part,
    float* __restrict__ u, int first, int last) {
    __shared__ float s_lds[4][NP];
    int tid = threadIdx.x, l = tid & 63, wv = tid >> 6;   // 4 waves
    int b = blockIdx.x >> 7;            // 128 blocks per batch
    int m0 = (blockIdx.x & 127) * 16;   // 16 rows per block
    float vreg[32];
    if (first) {
        #pragma unroll
        for (int i = 0; i < 32; ++i) vreg[i] = AB_CONST;
    } else {
        #pragma unroll
        for (int it = 0; it < 4; ++it) {
            float4 s0 = *(const float4*)(s_prev + b * NP + it * 512 + l * 8);
            float4 s1 = *(const float4*)(s_prev + b * NP + it * 512 + l * 8 + 4);
            vreg[it*8+0] = AB_CONST / (s0.x + 1e-8f);
            vreg[it*8+1] = AB_CONST / (s0.y + 1e-8f);
            vreg[it*8+2] = AB_CONST / (s0.z + 1e-8f);
            vreg[it*8+3] = AB_CONST / (s0.w + 1e-8f);
            vreg[it*8+4] = AB_CONST / (s1.x + 1e-8f);
            vreg[it*8+5] = AB_CONST / (s1.y + 1e-8f);
            vreg[it*8+6] = AB_CONST / (s1.z + 1e-8f);
            vreg[it*8+7] = AB_CONST / (s1.w + 1e-8f);
        }
    }
    float sreg[32];
    #pragma unroll
    for (int i = 0; i < 32; ++i) sreg[i] = 0.0f;
    #pragma unroll
    for (int rr = 0; rr < 4; ++rr) {
        int row = m0 + wv * 4 + rr;
        const u16* kp = Kx + ((size_t)(b * NP + row) << 11) + l * 8;
        uint4 kv0 = *(const uint4*)(kp);
        uint4 kv1 = *(const uint4*)(kp + 512);
        uint4 kv2 = *(const uint4*)(kp + 1024);
        uint4 kv3 = *(const uint4*)(kp + 1536);
        const u16* h0 = (const u16*)&kv0;
        const u16* h1 = (const u16*)&kv1;
        const u16* h2 = (const u16*)&kv2;
        const u16* h3 = (const u16*)&kv3;
        float p = 0.0f;
        #pragma unroll
        for (int j = 0; j < 8; ++j) {
            p += bf2f(h0[j]) * vreg[j];
            p += bf2f(h1[j]) * vreg[8 + j];
            p += bf2f(h2[j]) * vreg[16 + j];
            p += bf2f(h3[j]) * vreg[24 + j];
        }
        #pragma unroll
        for (int off = 32; off; off >>= 1) p += __shfl_xor(p, off);
        float um = AB_CONST / (p + 1e-8f);
        if (last && l == 0) u[b * NP + row] = um;
        #pragma unroll
        for (int j = 0; j < 8; ++j) {
            sreg[j]      += bf2f(h0[j]) * um;
            sreg[8 + j]  += bf2f(h1[j]) * um;
            sreg[16 + j] += bf2f(h2[j]) * um;
            sreg[24 + j] += bf2f(h3[j]) * um;
        }
    }
    // per-wave LDS region, each j written exactly once per wave
    #pragma unroll
    for (int it = 0; it < 4; ++it)
        #pragma unroll
        for (int j = 0; j < 8; ++j)
            s_lds[wv][it * 512 + l * 8 + j] = sreg[it * 8 + j];
    __syncthreads();
    // cross-wave sum, conflict-free (consecutive tid -> consecutive banks)
    #pragma unroll
    for (int e = 0; e < 8; ++e) {
        int j = e * 256 + tid;
        float acc = s_lds[0][j] + s_lds[1][j] + s_lds[2][j] + s_lds[3][j];
        part[(size_t)blockIdx.x * NP + j] = acc;
    }
}

// ---------------- Kernel 3b: reduce 128 partials per batch -> s ---------------
__global__ __launch_bounds__(256) void k_red(const float* __restrict__ part,
        float* __restrict__ s) {
    int tid = threadIdx.x;
    int b = blockIdx.x >> 3;                  // grid 64: 8 blocks per batch
    int j = (blockIdx.x & 7) * 256 + tid;
    const float* pp = part + (size_t)(b * 128) * NP + j;
    float a0 = 0.f, a1 = 0.f, a2 = 0.f, a3 = 0.f;
    #pragma unroll
    for (int p = 0; p < 128; p += 4) {
        a0 += pp[(size_t)(p + 0) * NP];
        a1 += pp[(size_t)(p + 1) * NP];
        a2 += pp[(size_t)(p + 2) * NP];
        a3 += pp[(size_t)(p + 3) * NP];
    }
    s[b * NP + j] = (a0 + a1) + (a2 + a3);
}

// ---------------- Kernel 4: finalize log u, log v -----------------------------
__global__ __launch_bounds__(256) void k_logs(const float* __restrict__ s_fin,
        const float* __restrict__ u, float* __restrict__ logu, float* __restrict__ logv) {
    int gid = blockIdx.x * 256 + threadIdx.x;   // grid 64
    float vv = AB_CONST / (s_fin[gid] + 1e-8f);
    logv[gid] = logf(vv);
    logu[gid] = logf(u[gid]);
}

// ---------------- Kernel 5: logits + partial online LSE (4 j-chunks) ----------
__global__ __launch_bounds__(256, 4) void k_loss(const u16* __restrict__ G,
    const float* __restrict__ rnq, const float* __restrict__ rnk,
    const float* __restrict__ logu, const float* __restrict__ logv,
    float* __restrict__ pmo, float* __restrict__ pso) {
    __shared__ float Grow[64 * 65];
    __shared__ float Tcol[64 * 65];
    __shared__ float lu_s[64], rq_s[64];
    __shared__ float pm[4][64], ps[4][64];
    int tid = threadIdx.x;
    int r = tid & 63, p = tid >> 6;
    int chunk = blockIdx.x;           // 0..3
    int i0 = blockIdx.y * 64;         // 0..31 tiles
    int b = blockIdx.z;               // 0..7
    int gi = b * NP + i0 + r;
    int iloc = i0 + r;
    float rki = rnk[gi];
    float lvc = logv[gi] + LOG2047;
    float m = -1e30f;
    float ssum = 0.0f;
    for (int jtl = 0; jtl < 8; ++jtl) {
        int jb = (chunk * 8 + jtl) * 64;
        __syncthreads();
        #pragma unroll
        for (int s2 = 0; s2 < 2; ++s2) {
            int qd = tid + s2 * 256;
            int rr = qd >> 3;
            int c8 = (qd & 7) * 8;
            uint4 gv = *(const uint4*)(G + ((size_t)(b * NP + i0 + rr) << 11) + jb + c8);
            const u16* hs = (const u16*)&gv;
            #pragma unroll
            for (int d = 0; d < 8; ++d) Grow[rr * 65 + c8 + d] = bf2f(hs[d]);
            uint4 cv = *(const uint4*)(G + ((size_t)(b * NP + jb + rr) << 11) + i0 + c8);
            const u16* hc = (const u16*)&cv;
            #pragma unroll
            for (int d = 0; d < 8; ++d) Tcol[(c8 + d) * 65 + rr] = bf2f(hc[d]);
        }
        if (tid < 64) {
            lu_s[tid] = logu[b * NP + jb + tid];
            rq_s[tid] = rnq[b * NP + jb + tid];
        }
        __syncthreads();
        int j0 = p * 16;
        #pragma unroll
        for (int jj = 0; jj < 16; ++jj) {
            int jc = j0 + jj;
            float gij = Grow[r * 65 + jc];
            float gji = Tcol[r * 65 + jc];
            float logit = gij * INV_T - gji * rq_s[jc] * rki + lu_s[jc] + lvc;
            if (iloc == jb + jc) logit = -10.0f * INV_T;
            if (logit <= m) {
                ssum += __expf(logit - m);
            } else {
                ssum = ssum * __expf(m - logit) + 1.0f;
                m = logit;
            }
        }
    }
    pm[p][r] = m; ps[p][r] = ssum;
    __syncthreads();
    if (tid < 64) {
        float M = pm[0][tid];
        #pragma unroll
        for (int pp = 1; pp < 4; ++pp) M = fmaxf(M, pm[pp][tid]);
        float S = 0.0f;
        #pragma unroll
        for (int pp = 0; pp < 4; ++pp) S += ps[pp][tid] * __expf(pm[pp][tid] - M);
        int row = b * NP + i0 + tid;
        pmo[row * 4 + chunk] = M;
        pso[row * 4 + chunk] = S;
    }
}

// ---------------- Kernel 6: combine partials + positive -> loss ---------------
__global__ __launch_bounds__(256) void k_comb(const float* __restrict__ pmo,
        const float* __restrict__ pso, const float* __restrict__ lpos,
        float* __restrict__ out) {
    int gid = blockIdx.x * 256 + threadIdx.x;   // grid 64
    float opos = lpos[gid] * INV_T;
    float M = opos, S = 1.0f;
    float4 m4 = *(const float4*)(pmo + gid * 4);
    float4 s4 = *(const float4*)(pso + gid * 4);
    float mv[4] = {m4.x, m4.y, m4.z, m4.w};
    float sv[4] = {s4.x, s4.y, s4.z, s4.w};
    #pragma unroll
    for (int c = 0; c < 4; ++c) {
        float Mn = fmaxf(M, mv[c]);
        S = S * __expf(M - Mn) + sv[c] * __expf(mv[c] - Mn);
        M = Mn;
    }
    out[gid] = M + logf(S) - opos;
}

extern "C" void kernel_launch(void* const* d_in, const int* in_sizes, int n_in,
                              void* d_out, int out_size, void* d_ws, size_t ws_size,
                              hipStream_t stream) {
    const float* q = (const float*)d_in[0];
    const float* k = (const float*)d_in[1];
    char* w = (char*)d_ws;
    u16* G    = (u16*)(w);                          // 67108864 B
    u16* Kx   = (u16*)(w + 67108864);               // 67108864 B
    u16* qb   = (u16*)(w + 134217728);              // 8388608 B (dead after k_gemm)
    float* part = (float*)(w + 134217728);          // overlaps qb: 1024*2048*4 = 8388608 B
    u16* kb   = (u16*)(w + 142606336);              // 8388608 B (dead after k_gemm)
    float* pmo  = (float*)(w + 142606336);          // overlaps kb
    float* pso  = (float*)(w + 142606336 + 262144);
    float* rnq  = (float*)(w + 150994944);
    float* rnk  = (float*)(w + 151060480);
    float* lpos = (float*)(w + 151126016);
    float* u    = (float*)(w + 151191552);
    float* logu = (float*)(w + 151257088);
    float* logv = (float*)(w + 151322624);
    float* s    = (float*)(w + 151388160);          // 65536 B
    float* out  = (float*)d_out;

    k_prep<<<4096, 256, 0, stream>>>(q, k, qb, kb, rnq, rnk, lpos);
    k_gemm<<<dim3(16, 16, 8), 256, 0, stream>>>(qb, kb, rnq, rnk, G, Kx);
    for (int t = 0; t < N_ITER; ++t) {
        k_sink<<<1024, 256, 0, stream>>>(Kx, s, part, u,
                                         t == 0 ? 1 : 0, t == N_ITER - 1 ? 1 : 0);
        k_red<<<64, 256, 0, stream>>>(part, s);
    }
    k_logs<<<64, 256, 0, stream>>>(s, u, logu, logv);
    k_loss<<<dim3(4, 32, 8), 256, 0, stream>>>(G, rnq, rnk, logu, logv, pmo, pso);
    k_comb<<<64, 256, 0, stream>>>(pmo, pso, lpos, out);
}